// Round 2
// baseline (306.454 us; speedup 1.0000x reference)
//
#include <hip/hip_runtime.h>
#include <stdint.h>

typedef unsigned short ushort_t;
typedef __attribute__((ext_vector_type(8))) short bf16x8;   // 8 bf16 = 4 VGPRs
typedef __attribute__((ext_vector_type(4))) float f32x4;
typedef __attribute__((ext_vector_type(16))) float f32x16;

__device__ __forceinline__ ushort_t f2bf(float f) {
  union { float f; unsigned u; } v; v.f = f;
  unsigned r = v.u + 0x7fffu + ((v.u >> 16) & 1u);
  return (ushort_t)(r >> 16);
}
__device__ __forceinline__ unsigned bfbits(float f) {
  union { float f; unsigned u; } v; v.f = f; return v.u;
}
// pack two floats' bf16 truncations: [hi.bf16 : lo.bf16]
__device__ __forceinline__ unsigned pack_trunc(float lo, float hi) {
#if __has_builtin(__builtin_amdgcn_perm)
  return __builtin_amdgcn_perm(bfbits(hi), bfbits(lo), 0x07060302u);
#else
  return (bfbits(lo) >> 16) | (bfbits(hi) & 0xffff0000u);
#endif
}
__device__ __forceinline__ unsigned pack_rn(float lo, float hi) {
  return (unsigned)f2bf(lo) | ((unsigned)f2bf(hi) << 16);
}
// v_permlane32_swap_b32: a.hi32lanes <-> b.lo32lanes (both updated)
__device__ __forceinline__ void swap32(unsigned &a, unsigned &b) {
#if __has_builtin(__builtin_amdgcn_permlane32_swap)
  auto r = __builtin_amdgcn_permlane32_swap(a, b, false, false);
  a = r[0]; b = r[1];
#else
  asm volatile("v_permlane32_swap_b32 %0, %1" : "+v"(a), "+v"(b));
#endif
}

#define SCALE_Q 0.18033688011112042f   /* 0.125 * log2(e) */
#define EXP_BIAS 23.083109273961734f   /* 16 * log2(e) */

// ---------- GroupNorm stats stage 1: 256 blocks x 16384 floats -------------
__global__ __launch_bounds__(256)
void gn_stats1(const float* __restrict__ x, float2* __restrict__ partial) {
  int blk = blockIdx.x, tid = threadIdx.x;
  const float* base = x + (size_t)blk * 16384;
  float s = 0.f, ss = 0.f;
  for (int i = tid * 4; i < 16384; i += 1024) {
    float4 v = *(const float4*)(base + i);
    s  += v.x + v.y + v.z + v.w;
    ss += v.x*v.x + v.y*v.y + v.z*v.z + v.w*v.w;
  }
  __shared__ float rs[256], rss[256];
  rs[tid] = s; rss[tid] = ss;
  __syncthreads();
  for (int off = 128; off > 0; off >>= 1) {
    if (tid < off) { rs[tid] += rs[tid+off]; rss[tid] += rss[tid+off]; }
    __syncthreads();
  }
  if (tid == 0) partial[blk] = make_float2(rs[0], rss[0]);
}

// ---------- GroupNorm stats stage 2: reduce 8 partials per (b,g) -----------
__global__ __launch_bounds__(64)
void gn_stats2(const float2* __restrict__ partial, float* __restrict__ stats) {
  int g = threadIdx.x;
  if (g < 32) {
    float s = 0.f, ss = 0.f;
    #pragma unroll
    for (int k = 0; k < 8; k++) { float2 p = partial[g*8 + k]; s += p.x; ss += p.y; }
    float mean = s * (1.f/131072.f);
    float var  = ss * (1.f/131072.f) - mean*mean;
    stats[g*2]   = mean;
    stats[g*2+1] = rsqrtf(var + 1e-5f);
  }
}

// -- normalize+transpose: x[b][c][n] -> xn_t[(b-b0)*4096+n][c] (bf16 chunk) -
__global__ __launch_bounds__(256)
void gn_apply_t(const float* __restrict__ x, const float* __restrict__ stats,
                const float* __restrict__ gamma, const float* __restrict__ beta,
                ushort_t* __restrict__ xn_t, int b0) {
  int blk = blockIdx.x;            // nb*128 = bl x nt(16) x ct(8)
  int tid = threadIdx.x;
  int ct = blk & 7;
  int nt = (blk >> 3) & 15;
  int bl = blk >> 7;               // local batch in chunk
  int b  = b0 + bl;                // global batch
  int c0 = ct * 32;                // one 32-ch group per tile (group == ct)
  float mean = stats[(b*8 + ct)*2];
  float rstd = stats[(b*8 + ct)*2 + 1];
  __shared__ ushort_t Ls[32][264];
  for (int idx = tid; idx < 32*64; idx += 256) {
    int cc = idx >> 6, seg = idx & 63;
    float ga = gamma[c0+cc], be = beta[c0+cc];
    float a = rstd * ga;
    float bb = be - mean * a;
    float4 v = *(const float4*)(x + ((size_t)(b*256 + c0 + cc))*4096 + nt*256 + seg*4);
    ushort4 t4 = make_ushort4(f2bf(v.x*a+bb), f2bf(v.y*a+bb), f2bf(v.z*a+bb), f2bf(v.w*a+bb));
    *(ushort4*)&Ls[cc][seg*4] = t4;
  }
  __syncthreads();
  for (int idx = tid; idx < 256*4; idx += 256) {
    int n = idx >> 2, seg = idx & 3;
    union { ushort_t u[8]; uint4 v; } pk;
    #pragma unroll
    for (int e = 0; e < 8; e++) pk.u[e] = Ls[seg*8 + e][n];
    *(uint4*)(xn_t + ((size_t)(bl*4096 + nt*256 + n))*256 + c0 + seg*8) = pk.v;
  }
}

// ------- fp32 -> bf16 weight convert, both weight tensors in one launch ----
__global__ __launch_bounds__(256)
void wconv2(const float* __restrict__ wq, const float* __restrict__ wp,
            ushort_t* __restrict__ oq, ushort_t* __restrict__ op) {
  int blk = blockIdx.x;            // 0-191: qkv (196608), 192-255: proj (65536)
  const float* w; ushort_t* o; int i;
  if (blk < 192) { w = wq; o = oq; i = blk*256 + threadIdx.x; }
  else           { w = wp; o = op; i = (blk-192)*256 + threadIdx.x; }
  float4 v = *(const float4*)(w + (size_t)i*4);
  *(ushort4*)(o + (size_t)i*4) = make_ushort4(f2bf(v.x), f2bf(v.y), f2bf(v.z), f2bf(v.w));
}

// ------- GEMM1: tile 128M x 64N. Q->q[tok][256] (scaled), K->k[tok][256],
//         V -> vt[b*4+h][d][tok] (transposed through LDS, one head/tile).
__global__ __launch_bounds__(256)
void gemm_qkv(const ushort_t* __restrict__ A, const ushort_t* __restrict__ Bt,
              const float* __restrict__ bias, ushort_t* __restrict__ q,
              ushort_t* __restrict__ kbuf, ushort_t* __restrict__ vt, int b0) {
  int blk = blockIdx.x;            // (nb*32)*12 = mt x nt(12)
  int nt = blk % 12, mt = blk / 12;
  int m0 = mt*128, n0 = nt*64;
  int tid = threadIdx.x;
  int wave = tid >> 6, lane = tid & 63, quad = lane >> 4, l16 = lane & 15;
  __shared__ ushort_t As[128][40];
  __shared__ ushort_t Bs[64][40];
  __shared__ ushort_t Lt[64][136];   // V transpose tile [d][tok]
  f32x4 acc[2][4];
  #pragma unroll
  for (int i = 0; i < 2; i++)
    #pragma unroll
    for (int j = 0; j < 4; j++) acc[i][j] = (f32x4){0.f,0.f,0.f,0.f};

  for (int k0 = 0; k0 < 256; k0 += 32) {
    #pragma unroll
    for (int i = tid; i < 512; i += 256) {
      int row = i >> 2, seg = i & 3;
      *(uint4*)&As[row][seg*8] = *(const uint4*)(A + (size_t)(m0+row)*256 + k0 + seg*8);
    }
    {
      int row = tid >> 2, seg = tid & 3;
      *(uint4*)&Bs[row][seg*8] = *(const uint4*)(Bt + (size_t)(n0+row)*256 + k0 + seg*8);
    }
    __syncthreads();
    bf16x8 af[2], bfr[4];
    #pragma unroll
    for (int t = 0; t < 2; t++) af[t]  = *(const bf16x8*)&As[wave*32 + t*16 + l16][quad*8];
    #pragma unroll
    for (int t = 0; t < 4; t++) bfr[t] = *(const bf16x8*)&Bs[t*16 + l16][quad*8];
    #pragma unroll
    for (int ti = 0; ti < 2; ti++)
      #pragma unroll
      for (int jn = 0; jn < 4; jn++)
        acc[ti][jn] = __builtin_amdgcn_mfma_f32_16x16x32_bf16(af[ti], bfr[jn], acc[ti][jn], 0, 0, 0);
    __syncthreads();
  }

  int region = nt >> 2;   // 0=Q (n<256), 1=K, 2=V
  if (region == 0) {
    #pragma unroll
    for (int jn = 0; jn < 4; jn++) {
      int n = n0 + jn*16 + l16;
      float bv = bias[n];
      #pragma unroll
      for (int ti = 0; ti < 2; ti++) {
        int mrow = m0 + wave*32 + ti*16 + quad*4;
        #pragma unroll
        for (int r = 0; r < 4; r++)
          q[(size_t)(b0*4096 + mrow + r)*256 + n] = f2bf((acc[ti][jn][r] + bv) * SCALE_Q);
      }
    }
  } else if (region == 1) {
    #pragma unroll
    for (int jn = 0; jn < 4; jn++) {
      int n = n0 + jn*16 + l16;
      float bv = bias[n];
      #pragma unroll
      for (int ti = 0; ti < 2; ti++) {
        int mrow = m0 + wave*32 + ti*16 + quad*4;
        #pragma unroll
        for (int r = 0; r < 4; r++)
          kbuf[(size_t)(b0*4096 + mrow + r)*256 + (n - 256)] = f2bf(acc[ti][jn][r] + bv);
      }
    }
  } else {
    int hh = nt - 8;                 // one head per 64-wide tile
    int b_loc = m0 >> 12;
    #pragma unroll
    for (int jn = 0; jn < 4; jn++) {
      int n = n0 + jn*16 + l16;
      float bv = bias[n];
      int drow = jn*16 + l16;        // d within head (0..63)
      #pragma unroll
      for (int ti = 0; ti < 2; ti++) {
        int tcol = wave*32 + ti*16 + quad*4;
        uint2 w;
        w.x = pack_rn(acc[ti][jn][0] + bv, acc[ti][jn][1] + bv);
        w.y = pack_rn(acc[ti][jn][2] + bv, acc[ti][jn][3] + bv);
        *(uint2*)&Lt[drow][tcol] = w;
      }
    }
    __syncthreads();
    size_t vb_ = ((size_t)((b0 + b_loc)*4 + hh)*64)*4096 + (size_t)(m0 & 4095);
    for (int idx = tid; idx < 1024; idx += 256) {
      int dd = idx >> 4, toff = (idx & 15)*8;
      *(uint4*)(vt + vb_ + (size_t)dd*4096 + toff) = *(const uint4*)&Lt[dd][toff];
    }
  }
}

// -------- flash attention v8: 32x32x16 MFMA, swapped QK^T, in-register P.
// Per wave: 32 queries. QK^T = mfma(K,Q) -> lane holds P[16 keys][own query];
// P -> PV B-operand fragments via 8x pack_trunc + 4x v_permlane32_swap_b32
// (no Ps LDS round-trip). Row-sum in VALU on the same truncated bf16 values
// (replaces the 'ones' MFMAs). 128-key LDS tiles double-buffered, ONE barrier
// per tile, staging split K-then-V.
// q[tok][256] (pre-scaled by 0.125*log2e), k[tok][256], vt[bh][d][tok].
// O overwrites q in place (disjoint rows per block -> race-free).
__global__ __launch_bounds__(256, 2)
void attn(ushort_t* __restrict__ q, const ushort_t* __restrict__ k,
          const ushort_t* __restrict__ vt) {
  int blk = blockIdx.x;            // nb*128 = b x h(4) x it(32)
  int it = blk & 31;
  int h  = (blk >> 5) & 3;
  int b  = blk >> 7;
  int i0 = it * 128;
  int tid = threadIdx.x;
  int wave = tid >> 6, lane = tid & 63;
  int q32 = lane & 31, hi = lane >> 5;

  __shared__ ushort_t Ks[2][128][72];   // [key][d]  stride 144B
  __shared__ ushort_t Vs[2][64][144];   // [d][key]  stride 288B

  const ushort_t* kbase = k + (size_t)(b*4096)*256 + h*64;
  const ushort_t* vbase = vt + (size_t)(b*4 + h)*64*4096;
  ushort_t* qrow = q + (size_t)(b*4096 + i0 + wave*32 + q32)*256 + h*64;

  // Q B-fragments: n = q32, k(d) = s*16 + hi*8 + e  (direct from global)
  bf16x8 qb[4];
  #pragma unroll
  for (int s = 0; s < 4; s++) {
    uint4 u = *(const uint4*)(qrow + s*16 + hi*8);
    qb[s] = *(const bf16x8*)&u;
  }

  f32x16 o_acc[2];                 // O^T frags: m = d (2 blocks of 32), n = query
  #pragma unroll
  for (int d = 0; d < 2; d++)
    #pragma unroll
    for (int r = 0; r < 16; r++) o_acc[d][r] = 0.f;
  float lsum = 0.f;

  int sr = tid >> 3, sc = (tid & 7) * 8;    // K staging: 32 rows x 8 16B-chunks
  int vr = tid >> 4, vc = (tid & 15) * 8;   // V staging: 16 rows x 16 16B-chunks
  uint4 rk[4], rv[4];
  #define LOADK(JT) { int j0n = (JT)*128; \
    rk[0] = *(const uint4*)(kbase + (size_t)(j0n + sr      )*256 + sc); \
    rk[1] = *(const uint4*)(kbase + (size_t)(j0n + sr + 32 )*256 + sc); \
    rk[2] = *(const uint4*)(kbase + (size_t)(j0n + sr + 64 )*256 + sc); \
    rk[3] = *(const uint4*)(kbase + (size_t)(j0n + sr + 96 )*256 + sc); }
  #define WRITEK(BI) { \
    *(uint4*)&Ks[BI][sr      ][sc] = rk[0]; \
    *(uint4*)&Ks[BI][sr + 32 ][sc] = rk[1]; \
    *(uint4*)&Ks[BI][sr + 64 ][sc] = rk[2]; \
    *(uint4*)&Ks[BI][sr + 96 ][sc] = rk[3]; }
  #define LOADV(JT) { int j0n = (JT)*128; \
    rv[0] = *(const uint4*)(vbase + (size_t)(vr     )*4096 + j0n + vc); \
    rv[1] = *(const uint4*)(vbase + (size_t)(vr + 16)*4096 + j0n + vc); \
    rv[2] = *(const uint4*)(vbase + (size_t)(vr + 32)*4096 + j0n + vc); \
    rv[3] = *(const uint4*)(vbase + (size_t)(vr + 48)*4096 + j0n + vc); }
  #define WRITEV(BI) { \
    *(uint4*)&Vs[BI][vr     ][vc] = rv[0]; \
    *(uint4*)&Vs[BI][vr + 16][vc] = rv[1]; \
    *(uint4*)&Vs[BI][vr + 32][vc] = rv[2]; \
    *(uint4*)&Vs[BI][vr + 48][vc] = rv[3]; }

  // One 32-key block: 4 QK MFMA, 16 exp2, in-reg P shuffle, 4 PV MFMA.
  // C-layout of QK^T: P[key = (JB) + (r&3) + 8*(r>>2) + 4*hi][query q32].
  // PV B-frag for k-step ks needs keys (JB) + ks*16 + hi*8 + e per lane.
  #define COMPUTE_SUB32(BI, JB) { \
    bf16x8 kb0 = *(const bf16x8*)&Ks[BI][(JB) + q32][hi*8]; \
    bf16x8 kb1 = *(const bf16x8*)&Ks[BI][(JB) + q32][16 + hi*8]; \
    bf16x8 kb2 = *(const bf16x8*)&Ks[BI][(JB) + q32][32 + hi*8]; \
    bf16x8 kb3 = *(const bf16x8*)&Ks[BI][(JB) + q32][48 + hi*8]; \
    f32x16 s_; \
    _Pragma("unroll") \
    for (int r = 0; r < 16; r++) s_[r] = -EXP_BIAS; \
    s_ = __builtin_amdgcn_mfma_f32_32x32x16_bf16(kb0, qb[0], s_, 0, 0, 0); \
    s_ = __builtin_amdgcn_mfma_f32_32x32x16_bf16(kb1, qb[1], s_, 0, 0, 0); \
    s_ = __builtin_amdgcn_mfma_f32_32x32x16_bf16(kb2, qb[2], s_, 0, 0, 0); \
    s_ = __builtin_amdgcn_mfma_f32_32x32x16_bf16(kb3, qb[3], s_, 0, 0, 0); \
    float pt[16]; \
    _Pragma("unroll") \
    for (int r = 0; r < 16; r++) { \
      float pe = __builtin_exp2f(s_[r]); \
      s_[r] = pe; \
      union { unsigned u; float f; } tv; tv.u = bfbits(pe) & 0xffff0000u; \
      pt[r] = tv.f; \
    } \
    lsum += ((((pt[0]+pt[1])+(pt[2]+pt[3])) + ((pt[4]+pt[5])+(pt[6]+pt[7]))) \
          + (((pt[8]+pt[9])+(pt[10]+pt[11])) + ((pt[12]+pt[13])+(pt[14]+pt[15])))); \
    unsigned pkA = pack_trunc(s_[0],  s_[1]),  pkB = pack_trunc(s_[2],  s_[3]); \
    unsigned pkC = pack_trunc(s_[4],  s_[5]),  pkD = pack_trunc(s_[6],  s_[7]); \
    unsigned pkE = pack_trunc(s_[8],  s_[9]),  pkF = pack_trunc(s_[10], s_[11]); \
    unsigned pkG = pack_trunc(s_[12], s_[13]), pkH = pack_trunc(s_[14], s_[15]); \
    swap32(pkA, pkC); swap32(pkB, pkD);   /* pb0 = keys JB+0..15  */ \
    swap32(pkE, pkG); swap32(pkF, pkH);   /* pb1 = keys JB+16..31 */ \
    union { unsigned u[4]; bf16x8 v; } pb0_, pb1_; \
    pb0_.u[0] = pkA; pb0_.u[1] = pkB; pb0_.u[2] = pkC; pb0_.u[3] = pkD; \
    pb1_.u[0] = pkE; pb1_.u[1] = pkF; pb1_.u[2] = pkG; pb1_.u[3] = pkH; \
    bf16x8 vb00 = *(const bf16x8*)&Vs[BI][q32     ][(JB) + hi*8]; \
    bf16x8 vb01 = *(const bf16x8*)&Vs[BI][q32     ][(JB) + 16 + hi*8]; \
    bf16x8 vb10 = *(const bf16x8*)&Vs[BI][32 + q32][(JB) + hi*8]; \
    bf16x8 vb11 = *(const bf16x8*)&Vs[BI][32 + q32][(JB) + 16 + hi*8]; \
    o_acc[0] = __builtin_amdgcn_mfma_f32_32x32x16_bf16(vb00, pb0_.v, o_acc[0], 0, 0, 0); \
    o_acc[0] = __builtin_amdgcn_mfma_f32_32x32x16_bf16(vb01, pb1_.v, o_acc[0], 0, 0, 0); \
    o_acc[1] = __builtin_amdgcn_mfma_f32_32x32x16_bf16(vb10, pb0_.v, o_acc[1], 0, 0, 0); \
    o_acc[1] = __builtin_amdgcn_mfma_f32_32x32x16_bf16(vb11, pb1_.v, o_acc[1], 0, 0, 0); \
  }

  LOADK(0); LOADV(0); WRITEK(0); WRITEV(0);
  __syncthreads();

  for (int jt = 0; jt < 32; jt++) {
    int cur = jt & 1;
    if (jt < 31) LOADK(jt + 1);        // K loads age across sub 0,32
    COMPUTE_SUB32(cur, 0)
    COMPUTE_SUB32(cur, 32)
    if (jt < 31) { WRITEK(cur ^ 1); LOADV(jt + 1); }   // V loads age across sub 64,96
    COMPUTE_SUB32(cur, 64)
    COMPUTE_SUB32(cur, 96)
    if (jt < 31) WRITEV(cur ^ 1);
    __syncthreads();                   // nxt written, cur reads done
  }
  #undef LOADK
  #undef LOADV
  #undef WRITEK
  #undef WRITEV
  #undef COMPUTE_SUB32

  // lane(l) + lane(l^32) partial row sums -> total (permlane, no LDS)
  unsigned ua = __float_as_uint(lsum), ub = ua;
  swap32(ua, ub);
  float ltot = __uint_as_float(ua) + __uint_as_float(ub);
  float inv = 1.f / ltot;

  // O^T frag: n = q32 (row), m = d = dblk*32 + (r&3) + 8*(r>>2) + 4*hi
  #pragma unroll
  for (int dblk = 0; dblk < 2; dblk++)
    #pragma unroll
    for (int g = 0; g < 4; g++) {
      ushort4 u;
      u.x = f2bf(o_acc[dblk][g*4+0]*inv); u.y = f2bf(o_acc[dblk][g*4+1]*inv);
      u.z = f2bf(o_acc[dblk][g*4+2]*inv); u.w = f2bf(o_acc[dblk][g*4+3]*inv);
      *(ushort4*)(qrow + dblk*32 + g*8 + hi*4) = u;
    }
}

// - GEMM2: tile 128M x 64N. out[col][o] = sum_c wp[o][c]*O[col][c]+bias+resid
// O lives in q buffer, stride 256.
__global__ __launch_bounds__(256)
void gemm_proj(const ushort_t* __restrict__ A,    // wproj_bf [256][256]
               const ushort_t* __restrict__ Bt,   // q (O) [*][256]
               const float* __restrict__ bias, const float* __restrict__ resid,
               float* __restrict__ out, int col_base) {
  int blk = blockIdx.x;            // nb*128 = mt(2) x nt(nb*64)
  int mt = blk & 1, nt = blk >> 1;
  int m0 = mt*128, n0 = nt*64;
  int tid = threadIdx.x;
  int wave = tid >> 6, lane = tid & 63, quad = lane >> 4, l16 = lane & 15;
  __shared__ ushort_t As[128][40];
  __shared__ ushort_t Bs[64][40];
  f32x4 acc[2][4];
  #pragma unroll
  for (int i = 0; i < 2; i++)
    #pragma unroll
    for (int j = 0; j < 4; j++) acc[i][j] = (f32x4){0.f,0.f,0.f,0.f};

  for (int k0 = 0; k0 < 256; k0 += 32) {
    #pragma unroll
    for (int i = tid; i < 512; i += 256) {
      int row = i >> 2, seg = i & 3;
      *(uint4*)&As[row][seg*8] = *(const uint4*)(A + (size_t)(m0+row)*256 + k0 + seg*8);
    }
    {
      int row = tid >> 2, seg = tid & 3;
      *(uint4*)&Bs[row][seg*8] = *(const uint4*)(Bt + (size_t)(n0+row)*256 + k0 + seg*8);
    }
    __syncthreads();
    bf16x8 af[2], bfr[4];
    #pragma unroll
    for (int t = 0; t < 2; t++) af[t]  = *(const bf16x8*)&As[wave*32 + t*16 + l16][quad*8];
    #pragma unroll
    for (int t = 0; t < 4; t++) bfr[t] = *(const bf16x8*)&Bs[t*16 + l16][quad*8];
    #pragma unroll
    for (int ti = 0; ti < 2; ti++)
      #pragma unroll
      for (int jn = 0; jn < 4; jn++)
        acc[ti][jn] = __builtin_amdgcn_mfma_f32_16x16x32_bf16(af[ti], bfr[jn], acc[ti][jn], 0, 0, 0);
    __syncthreads();
  }
  #pragma unroll
  for (int jn = 0; jn < 4; jn++) {
    int col = col_base + n0 + jn*16 + l16;
    int bb = col >> 12;
    int np = col & 4095;
    #pragma unroll
    for (int ti = 0; ti < 2; ti++) {
      int o = m0 + wave*32 + ti*16 + quad*4;
      #pragma unroll
      for (int r = 0; r < 4; r++) {
        int oo = o + r;
        size_t addr = ((size_t)(bb*256 + oo))*4096 + np;
        out[addr] = acc[ti][jn][r] + bias[oo] + resid[addr];
      }
    }
  }
}

extern "C" void kernel_launch(void* const* d_in, const int* in_sizes, int n_in,
                              void* d_out, int out_size, void* d_ws, size_t ws_size,
                              hipStream_t stream) {
  const float* x      = (const float*)d_in[0];
  const float* gamma  = (const float*)d_in[1];
  const float* beta   = (const float*)d_in[2];
  const float* w_qkv  = (const float*)d_in[3];
  const float* b_qkv  = (const float*)d_in[4];
  const float* w_proj = (const float*)d_in[5];
  const float* b_proj = (const float*)d_in[6];
  float* out = (float*)d_out;

  char* ws = (char*)d_ws;
  float*  stats    = (float*)ws;                   // 256 B
  float2* partial  = (float2*)(ws + 1024);         // 2048 B
  ushort_t* wqkv_bf  = (ushort_t*)(ws + 4096);     // 393216 B
  ushort_t* wproj_bf = (ushort_t*)(ws + 397312);   // 131072 B
  char* big = ws + 528384;

  gn_stats1<<<dim3(256), dim3(256), 0, stream>>>(x, partial);
  gn_stats2<<<dim3(1), dim3(64), 0, stream>>>(partial, stats);
  wconv2<<<dim3(256), dim3(256), 0, stream>>>(w_qkv, w_proj, wqkv_bf, wproj_bf);

  // Full path: q 8.39M + k 8.39M + vt 8.39M + xn(nb=2) 4.19M = 29,888,512 B.
  if (ws_size >= (size_t)528384 + 3*(size_t)8388608 + (size_t)4194304) {
    ushort_t* q    = (ushort_t*)big;
    ushort_t* kbuf = (ushort_t*)(big + (size_t)8388608);
    ushort_t* vt   = (ushort_t*)(big + (size_t)16777216);
    ushort_t* xn   = (ushort_t*)(big + (size_t)25165824);
    for (int c = 0; c < 2; c++) {
      int b0 = c * 2;
      gn_apply_t<<<dim3(256), dim3(256), 0, stream>>>(x, stats, gamma, beta, xn, b0);
      gemm_qkv<<<dim3(768), dim3(256), 0, stream>>>(xn, wqkv_bf, b_qkv, q, kbuf, vt, b0);
    }
    attn<<<dim3(512), dim3(256), 0, stream>>>(q, kbuf, vt);
    gemm_proj<<<dim3(512), dim3(256), 0, stream>>>(wproj_bf, q, b_proj, x, out, 0);
  } else {
    // Per-batch fallback: 4 x 2.1M = 8.4M after fixed region.
    ushort_t* q_c  = (ushort_t*)big;
    ushort_t* k_c  = (ushort_t*)(big + (size_t)2097152);
    ushort_t* vt_c = (ushort_t*)(big + (size_t)4194304);
    ushort_t* xn_c = (ushort_t*)(big + (size_t)6291456);
    for (int b0 = 0; b0 < 4; b0++) {
      gn_apply_t<<<dim3(128), dim3(256), 0, stream>>>(x, stats, gamma, beta, xn_c, b0);
      gemm_qkv<<<dim3(384), dim3(256), 0, stream>>>(xn_c, wqkv_bf, b_qkv, q_c, k_c, vt_c, 0);
      attn<<<dim3(128), dim3(256), 0, stream>>>(q_c, k_c, vt_c);
      gemm_proj<<<dim3(128), dim3(256), 0, stream>>>(wproj_bf, q_c, b_proj, x, out, b0*4096);
    }
  }
}

// Round 3
// 245.479 us; speedup vs baseline: 1.2484x; 1.2484x over previous
//
#include <hip/hip_runtime.h>
#include <stdint.h>

typedef unsigned short ushort_t;
typedef __attribute__((ext_vector_type(8))) short bf16x8;   // 8 bf16 = 4 VGPRs
typedef __attribute__((ext_vector_type(4))) float f32x4;
typedef __attribute__((ext_vector_type(16))) float f32x16;
typedef __attribute__((ext_vector_type(4))) unsigned int u32x4;

__device__ __forceinline__ ushort_t f2bf(float f) {
  union { float f; unsigned u; } v; v.f = f;
  unsigned r = v.u + 0x7fffu + ((v.u >> 16) & 1u);
  return (ushort_t)(r >> 16);
}
__device__ __forceinline__ unsigned bfbits(float f) {
  union { float f; unsigned u; } v; v.f = f; return v.u;
}
// pack two floats' bf16 truncations: [hi.bf16 : lo.bf16]
__device__ __forceinline__ unsigned pack_trunc(float lo, float hi) {
#if __has_builtin(__builtin_amdgcn_perm)
  return __builtin_amdgcn_perm(bfbits(hi), bfbits(lo), 0x07060302u);
#else
  return (bfbits(lo) >> 16) | (bfbits(hi) & 0xffff0000u);
#endif
}
__device__ __forceinline__ unsigned pack_rn(float lo, float hi) {
  return (unsigned)f2bf(lo) | ((unsigned)f2bf(hi) << 16);
}
// v_permlane32_swap_b32: a.hi32lanes <-> b.lo32lanes (both updated)
__device__ __forceinline__ void swap32(unsigned &a, unsigned &b) {
#if __has_builtin(__builtin_amdgcn_permlane32_swap)
  auto r = __builtin_amdgcn_permlane32_swap(a, b, false, false);
  a = r[0]; b = r[1];
#else
  asm volatile("v_permlane32_swap_b32 %0, %1" : "+v"(a), "+v"(b));
#endif
}
// sum of the two bf16 values truncated-packed in pk
__device__ __forceinline__ float pksum(unsigned pk) {
  return __uint_as_float(pk << 16) + __uint_as_float(pk & 0xffff0000u);
}

#define SCALE_Q 0.18033688011112042f   /* 0.125 * log2(e) */
#define EXP_BIAS 23.083109273961734f   /* 16 * log2(e) */

// ---------- GroupNorm stats stage 1: 256 blocks x 16384 floats -------------
__global__ __launch_bounds__(256)
void gn_stats1(const float* __restrict__ x, float2* __restrict__ partial) {
  int blk = blockIdx.x, tid = threadIdx.x;
  const float* base = x + (size_t)blk * 16384;
  float s = 0.f, ss = 0.f;
  for (int i = tid * 4; i < 16384; i += 1024) {
    float4 v = *(const float4*)(base + i);
    s  += v.x + v.y + v.z + v.w;
    ss += v.x*v.x + v.y*v.y + v.z*v.z + v.w*v.w;
  }
  __shared__ float rs[256], rss[256];
  rs[tid] = s; rss[tid] = ss;
  __syncthreads();
  for (int off = 128; off > 0; off >>= 1) {
    if (tid < off) { rs[tid] += rs[tid+off]; rss[tid] += rss[tid+off]; }
    __syncthreads();
  }
  if (tid == 0) partial[blk] = make_float2(rs[0], rss[0]);
}

// ---------- GroupNorm stats stage 2: reduce 8 partials per (b,g) -----------
__global__ __launch_bounds__(64)
void gn_stats2(const float2* __restrict__ partial, float* __restrict__ stats) {
  int g = threadIdx.x;
  if (g < 32) {
    float s = 0.f, ss = 0.f;
    #pragma unroll
    for (int k = 0; k < 8; k++) { float2 p = partial[g*8 + k]; s += p.x; ss += p.y; }
    float mean = s * (1.f/131072.f);
    float var  = ss * (1.f/131072.f) - mean*mean;
    stats[g*2]   = mean;
    stats[g*2+1] = rsqrtf(var + 1e-5f);
  }
}

// -- normalize+transpose: x[b][c][n] -> xn_t[(b-b0)*4096+n][c] (bf16 chunk) -
__global__ __launch_bounds__(256)
void gn_apply_t(const float* __restrict__ x, const float* __restrict__ stats,
                const float* __restrict__ gamma, const float* __restrict__ beta,
                ushort_t* __restrict__ xn_t, int b0) {
  int blk = blockIdx.x;            // nb*128 = bl x nt(16) x ct(8)
  int tid = threadIdx.x;
  int ct = blk & 7;
  int nt = (blk >> 3) & 15;
  int bl = blk >> 7;               // local batch in chunk
  int b  = b0 + bl;                // global batch
  int c0 = ct * 32;                // one 32-ch group per tile (group == ct)
  float mean = stats[(b*8 + ct)*2];
  float rstd = stats[(b*8 + ct)*2 + 1];
  __shared__ ushort_t Ls[32][264];
  for (int idx = tid; idx < 32*64; idx += 256) {
    int cc = idx >> 6, seg = idx & 63;
    float ga = gamma[c0+cc], be = beta[c0+cc];
    float a = rstd * ga;
    float bb = be - mean * a;
    float4 v = *(const float4*)(x + ((size_t)(b*256 + c0 + cc))*4096 + nt*256 + seg*4);
    ushort4 t4 = make_ushort4(f2bf(v.x*a+bb), f2bf(v.y*a+bb), f2bf(v.z*a+bb), f2bf(v.w*a+bb));
    *(ushort4*)&Ls[cc][seg*4] = t4;
  }
  __syncthreads();
  for (int idx = tid; idx < 256*4; idx += 256) {
    int n = idx >> 2, seg = idx & 3;
    union { ushort_t u[8]; uint4 v; } pk;
    #pragma unroll
    for (int e = 0; e < 8; e++) pk.u[e] = Ls[seg*8 + e][n];
    *(uint4*)(xn_t + ((size_t)(bl*4096 + nt*256 + n))*256 + c0 + seg*8) = pk.v;
  }
}

// ------- fp32 -> bf16 weight convert, both weight tensors in one launch ----
__global__ __launch_bounds__(256)
void wconv2(const float* __restrict__ wq, const float* __restrict__ wp,
            ushort_t* __restrict__ oq, ushort_t* __restrict__ op) {
  int blk = blockIdx.x;            // 0-191: qkv (196608), 192-255: proj (65536)
  const float* w; ushort_t* o; int i;
  if (blk < 192) { w = wq; o = oq; i = blk*256 + threadIdx.x; }
  else           { w = wp; o = op; i = (blk-192)*256 + threadIdx.x; }
  float4 v = *(const float4*)(w + (size_t)i*4);
  *(ushort4*)(o + (size_t)i*4) = make_ushort4(f2bf(v.x), f2bf(v.y), f2bf(v.z), f2bf(v.w));
}

// ------- GEMM1: tile 128M x 64N. Q->q[tok][256] (scaled), K->k[tok][256],
//         V -> vt[b*4+h][d][tok] (transposed through LDS, one head/tile).
__global__ __launch_bounds__(256)
void gemm_qkv(const ushort_t* __restrict__ A, const ushort_t* __restrict__ Bt,
              const float* __restrict__ bias, ushort_t* __restrict__ q,
              ushort_t* __restrict__ kbuf, ushort_t* __restrict__ vt, int b0) {
  int blk = blockIdx.x;            // (nb*32)*12 = mt x nt(12)
  int nt = blk % 12, mt = blk / 12;
  int m0 = mt*128, n0 = nt*64;
  int tid = threadIdx.x;
  int wave = tid >> 6, lane = tid & 63, quad = lane >> 4, l16 = lane & 15;
  __shared__ ushort_t As[128][40];
  __shared__ ushort_t Bs[64][40];
  __shared__ ushort_t Lt[64][136];   // V transpose tile [d][tok]
  f32x4 acc[2][4];
  #pragma unroll
  for (int i = 0; i < 2; i++)
    #pragma unroll
    for (int j = 0; j < 4; j++) acc[i][j] = (f32x4){0.f,0.f,0.f,0.f};

  for (int k0 = 0; k0 < 256; k0 += 32) {
    #pragma unroll
    for (int i = tid; i < 512; i += 256) {
      int row = i >> 2, seg = i & 3;
      *(uint4*)&As[row][seg*8] = *(const uint4*)(A + (size_t)(m0+row)*256 + k0 + seg*8);
    }
    {
      int row = tid >> 2, seg = tid & 3;
      *(uint4*)&Bs[row][seg*8] = *(const uint4*)(Bt + (size_t)(n0+row)*256 + k0 + seg*8);
    }
    __syncthreads();
    bf16x8 af[2], bfr[4];
    #pragma unroll
    for (int t = 0; t < 2; t++) af[t]  = *(const bf16x8*)&As[wave*32 + t*16 + l16][quad*8];
    #pragma unroll
    for (int t = 0; t < 4; t++) bfr[t] = *(const bf16x8*)&Bs[t*16 + l16][quad*8];
    #pragma unroll
    for (int ti = 0; ti < 2; ti++)
      #pragma unroll
      for (int jn = 0; jn < 4; jn++)
        acc[ti][jn] = __builtin_amdgcn_mfma_f32_16x16x32_bf16(af[ti], bfr[jn], acc[ti][jn], 0, 0, 0);
    __syncthreads();
  }

  int region = nt >> 2;   // 0=Q (n<256), 1=K, 2=V
  if (region == 0) {
    #pragma unroll
    for (int jn = 0; jn < 4; jn++) {
      int n = n0 + jn*16 + l16;
      float bv = bias[n];
      #pragma unroll
      for (int ti = 0; ti < 2; ti++) {
        int mrow = m0 + wave*32 + ti*16 + quad*4;
        #pragma unroll
        for (int r = 0; r < 4; r++)
          q[(size_t)(b0*4096 + mrow + r)*256 + n] = f2bf((acc[ti][jn][r] + bv) * SCALE_Q);
      }
    }
  } else if (region == 1) {
    #pragma unroll
    for (int jn = 0; jn < 4; jn++) {
      int n = n0 + jn*16 + l16;
      float bv = bias[n];
      #pragma unroll
      for (int ti = 0; ti < 2; ti++) {
        int mrow = m0 + wave*32 + ti*16 + quad*4;
        #pragma unroll
        for (int r = 0; r < 4; r++)
          kbuf[(size_t)(b0*4096 + mrow + r)*256 + (n - 256)] = f2bf(acc[ti][jn][r] + bv);
      }
    }
  } else {
    int hh = nt - 8;                 // one head per 64-wide tile
    int b_loc = m0 >> 12;
    #pragma unroll
    for (int jn = 0; jn < 4; jn++) {
      int n = n0 + jn*16 + l16;
      float bv = bias[n];
      int drow = jn*16 + l16;        // d within head (0..63)
      #pragma unroll
      for (int ti = 0; ti < 2; ti++) {
        int tcol = wave*32 + ti*16 + quad*4;
        uint2 w;
        w.x = pack_rn(acc[ti][jn][0] + bv, acc[ti][jn][1] + bv);
        w.y = pack_rn(acc[ti][jn][2] + bv, acc[ti][jn][3] + bv);
        *(uint2*)&Lt[drow][tcol] = w;
      }
    }
    __syncthreads();
    size_t vb_ = ((size_t)((b0 + b_loc)*4 + hh)*64)*4096 + (size_t)(m0 & 4095);
    for (int idx = tid; idx < 1024; idx += 256) {
      int dd = idx >> 4, toff = (idx & 15)*8;
      *(uint4*)(vt + vb_ + (size_t)dd*4096 + toff) = *(const uint4*)&Lt[dd][toff];
    }
  }
}

// -------- flash attention v9: 32x32x16 MFMA, swapped QK^T, in-register P.
// v8 regressed: pt[16] array + bf16x8 unions inside the 4x-expanded macro
// defeated SROA -> scratch (WRITE_SIZE 8MB -> 360MB, VGPR 88). v9 keeps the
// identical schedule/numerics but builds everything from scalars + bit_cast:
//   - lsum accumulated straight from the packed bf16 words (pre-swap)
//   - PV B-fragments via __builtin_bit_cast(bf16x8, u32x4{...})
//   - Q fragments as 4 named scalars, direct 16B deref
// q[tok][256] (pre-scaled by 0.125*log2e), k[tok][256], vt[bh][d][tok].
// O overwrites q in place (disjoint rows per block -> race-free).
__global__ __launch_bounds__(256, 2)
void attn(ushort_t* __restrict__ q, const ushort_t* __restrict__ k,
          const ushort_t* __restrict__ vt) {
  int blk = blockIdx.x;            // nb*128 = b x h(4) x it(32)
  int it = blk & 31;
  int h  = (blk >> 5) & 3;
  int b  = blk >> 7;
  int i0 = it * 128;
  int tid = threadIdx.x;
  int wave = tid >> 6, lane = tid & 63;
  int q32 = lane & 31, hi = lane >> 5;

  __shared__ ushort_t Ks[2][128][72];   // [key][d]  stride 144B
  __shared__ ushort_t Vs[2][64][144];   // [d][key]  stride 288B

  const ushort_t* kbase = k + (size_t)(b*4096)*256 + h*64;
  const ushort_t* vbase = vt + (size_t)(b*4 + h)*64*4096;
  ushort_t* qrow = q + (size_t)(b*4096 + i0 + wave*32 + q32)*256 + h*64;

  // Q B-fragments: n = q32, k(d) = s*16 + hi*8 + e  (direct from global)
  bf16x8 qb0 = *(const bf16x8*)(qrow      + hi*8);
  bf16x8 qb1 = *(const bf16x8*)(qrow + 16 + hi*8);
  bf16x8 qb2 = *(const bf16x8*)(qrow + 32 + hi*8);
  bf16x8 qb3 = *(const bf16x8*)(qrow + 48 + hi*8);

  f32x16 o_acc0, o_acc1;           // O^T frags: m = d (2 blocks of 32), n = query
  #pragma unroll
  for (int r = 0; r < 16; r++) { o_acc0[r] = 0.f; o_acc1[r] = 0.f; }
  float lsum = 0.f;

  int sr = tid >> 3, sc = (tid & 7) * 8;    // K staging: 32 rows x 8 16B-chunks
  int vr = tid >> 4, vc = (tid & 15) * 8;   // V staging: 16 rows x 16 16B-chunks
  uint4 rk0, rk1, rk2, rk3, rv0, rv1, rv2, rv3;
  #define LOADK(JT) { int j0n = (JT)*128; \
    rk0 = *(const uint4*)(kbase + (size_t)(j0n + sr      )*256 + sc); \
    rk1 = *(const uint4*)(kbase + (size_t)(j0n + sr + 32 )*256 + sc); \
    rk2 = *(const uint4*)(kbase + (size_t)(j0n + sr + 64 )*256 + sc); \
    rk3 = *(const uint4*)(kbase + (size_t)(j0n + sr + 96 )*256 + sc); }
  #define WRITEK(BI) { \
    *(uint4*)&Ks[BI][sr      ][sc] = rk0; \
    *(uint4*)&Ks[BI][sr + 32 ][sc] = rk1; \
    *(uint4*)&Ks[BI][sr + 64 ][sc] = rk2; \
    *(uint4*)&Ks[BI][sr + 96 ][sc] = rk3; }
  #define LOADV(JT) { int j0n = (JT)*128; \
    rv0 = *(const uint4*)(vbase + (size_t)(vr     )*4096 + j0n + vc); \
    rv1 = *(const uint4*)(vbase + (size_t)(vr + 16)*4096 + j0n + vc); \
    rv2 = *(const uint4*)(vbase + (size_t)(vr + 32)*4096 + j0n + vc); \
    rv3 = *(const uint4*)(vbase + (size_t)(vr + 48)*4096 + j0n + vc); }
  #define WRITEV(BI) { \
    *(uint4*)&Vs[BI][vr     ][vc] = rv0; \
    *(uint4*)&Vs[BI][vr + 16][vc] = rv1; \
    *(uint4*)&Vs[BI][vr + 32][vc] = rv2; \
    *(uint4*)&Vs[BI][vr + 48][vc] = rv3; }

  // One 32-key block: 4 QK MFMA, 16 exp2, in-reg P shuffle, 4 PV MFMA.
  // C-layout of QK^T: P[key = (JB) + (r&3) + 8*(r>>2) + 4*hi][query q32].
  // PV B-frag for k-step ks needs keys (JB) + ks*16 + hi*8 + e per lane.
  #define COMPUTE_SUB32(BI, JB) { \
    bf16x8 kb0 = *(const bf16x8*)&Ks[BI][(JB) + q32][hi*8]; \
    bf16x8 kb1 = *(const bf16x8*)&Ks[BI][(JB) + q32][16 + hi*8]; \
    bf16x8 kb2 = *(const bf16x8*)&Ks[BI][(JB) + q32][32 + hi*8]; \
    bf16x8 kb3 = *(const bf16x8*)&Ks[BI][(JB) + q32][48 + hi*8]; \
    f32x16 s_; \
    _Pragma("unroll") \
    for (int r = 0; r < 16; r++) s_[r] = -EXP_BIAS; \
    s_ = __builtin_amdgcn_mfma_f32_32x32x16_bf16(kb0, qb0, s_, 0, 0, 0); \
    s_ = __builtin_amdgcn_mfma_f32_32x32x16_bf16(kb1, qb1, s_, 0, 0, 0); \
    s_ = __builtin_amdgcn_mfma_f32_32x32x16_bf16(kb2, qb2, s_, 0, 0, 0); \
    s_ = __builtin_amdgcn_mfma_f32_32x32x16_bf16(kb3, qb3, s_, 0, 0, 0); \
    _Pragma("unroll") \
    for (int r = 0; r < 16; r++) s_[r] = __builtin_exp2f(s_[r]); \
    unsigned pkA = pack_trunc(s_[0],  s_[1]),  pkB = pack_trunc(s_[2],  s_[3]); \
    unsigned pkC = pack_trunc(s_[4],  s_[5]),  pkD = pack_trunc(s_[6],  s_[7]); \
    unsigned pkE = pack_trunc(s_[8],  s_[9]),  pkF = pack_trunc(s_[10], s_[11]); \
    unsigned pkG = pack_trunc(s_[12], s_[13]), pkH = pack_trunc(s_[14], s_[15]); \
    lsum += (((pksum(pkA) + pksum(pkB)) + (pksum(pkC) + pksum(pkD))) \
           + ((pksum(pkE) + pksum(pkF)) + (pksum(pkG) + pksum(pkH)))); \
    swap32(pkA, pkC); swap32(pkB, pkD);   /* pb0 = keys JB+0..15  */ \
    swap32(pkE, pkG); swap32(pkF, pkH);   /* pb1 = keys JB+16..31 */ \
    u32x4 w0_ = {pkA, pkB, pkC, pkD}; \
    u32x4 w1_ = {pkE, pkF, pkG, pkH}; \
    bf16x8 pb0 = __builtin_bit_cast(bf16x8, w0_); \
    bf16x8 pb1 = __builtin_bit_cast(bf16x8, w1_); \
    bf16x8 vb00 = *(const bf16x8*)&Vs[BI][q32     ][(JB) + hi*8]; \
    bf16x8 vb01 = *(const bf16x8*)&Vs[BI][q32     ][(JB) + 16 + hi*8]; \
    bf16x8 vb10 = *(const bf16x8*)&Vs[BI][32 + q32][(JB) + hi*8]; \
    bf16x8 vb11 = *(const bf16x8*)&Vs[BI][32 + q32][(JB) + 16 + hi*8]; \
    o_acc0 = __builtin_amdgcn_mfma_f32_32x32x16_bf16(vb00, pb0, o_acc0, 0, 0, 0); \
    o_acc0 = __builtin_amdgcn_mfma_f32_32x32x16_bf16(vb01, pb1, o_acc0, 0, 0, 0); \
    o_acc1 = __builtin_amdgcn_mfma_f32_32x32x16_bf16(vb10, pb0, o_acc1, 0, 0, 0); \
    o_acc1 = __builtin_amdgcn_mfma_f32_32x32x16_bf16(vb11, pb1, o_acc1, 0, 0, 0); \
  }

  LOADK(0); LOADV(0); WRITEK(0); WRITEV(0);
  __syncthreads();

  for (int jt = 0; jt < 32; jt++) {
    int cur = jt & 1;
    if (jt < 31) LOADK(jt + 1);        // K loads age across sub 0,32
    COMPUTE_SUB32(cur, 0)
    COMPUTE_SUB32(cur, 32)
    if (jt < 31) { WRITEK(cur ^ 1); LOADV(jt + 1); }   // V loads age across sub 64,96
    COMPUTE_SUB32(cur, 64)
    COMPUTE_SUB32(cur, 96)
    if (jt < 31) WRITEV(cur ^ 1);
    __syncthreads();                   // nxt written, cur reads done
  }
  #undef LOADK
  #undef LOADV
  #undef WRITEK
  #undef WRITEV
  #undef COMPUTE_SUB32

  // lane(l) + lane(l^32) partial row sums -> total (permlane, no LDS)
  unsigned ua = __float_as_uint(lsum), ub = ua;
  swap32(ua, ub);
  float ltot = __uint_as_float(ua) + __uint_as_float(ub);
  float inv = 1.f / ltot;

  // O^T frag: n = q32 (row), m = d = dblk*32 + g*8 + hi*4 + r
  #pragma unroll
  for (int g = 0; g < 4; g++) {
    ushort4 u;
    u.x = f2bf(o_acc0[g*4+0]*inv); u.y = f2bf(o_acc0[g*4+1]*inv);
    u.z = f2bf(o_acc0[g*4+2]*inv); u.w = f2bf(o_acc0[g*4+3]*inv);
    *(ushort4*)(qrow + g*8 + hi*4) = u;
  }
  #pragma unroll
  for (int g = 0; g < 4; g++) {
    ushort4 u;
    u.x = f2bf(o_acc1[g*4+0]*inv); u.y = f2bf(o_acc1[g*4+1]*inv);
    u.z = f2bf(o_acc1[g*4+2]*inv); u.w = f2bf(o_acc1[g*4+3]*inv);
    *(ushort4*)(qrow + 32 + g*8 + hi*4) = u;
  }
}

// - GEMM2: tile 128M x 64N. out[col][o] = sum_c wp[o][c]*O[col][c]+bias+resid
// O lives in q buffer, stride 256.
__global__ __launch_bounds__(256)
void gemm_proj(const ushort_t* __restrict__ A,    // wproj_bf [256][256]
               const ushort_t* __restrict__ Bt,   // q (O) [*][256]
               const float* __restrict__ bias, const float* __restrict__ resid,
               float* __restrict__ out, int col_base) {
  int blk = blockIdx.x;            // nb*128 = mt(2) x nt(nb*64)
  int mt = blk & 1, nt = blk >> 1;
  int m0 = mt*128, n0 = nt*64;
  int tid = threadIdx.x;
  int wave = tid >> 6, lane = tid & 63, quad = lane >> 4, l16 = lane & 15;
  __shared__ ushort_t As[128][40];
  __shared__ ushort_t Bs[64][40];
  f32x4 acc[2][4];
  #pragma unroll
  for (int i = 0; i < 2; i++)
    #pragma unroll
    for (int j = 0; j < 4; j++) acc[i][j] = (f32x4){0.f,0.f,0.f,0.f};

  for (int k0 = 0; k0 < 256; k0 += 32) {
    #pragma unroll
    for (int i = tid; i < 512; i += 256) {
      int row = i >> 2, seg = i & 3;
      *(uint4*)&As[row][seg*8] = *(const uint4*)(A + (size_t)(m0+row)*256 + k0 + seg*8);
    }
    {
      int row = tid >> 2, seg = tid & 3;
      *(uint4*)&Bs[row][seg*8] = *(const uint4*)(Bt + (size_t)(n0+row)*256 + k0 + seg*8);
    }
    __syncthreads();
    bf16x8 af[2], bfr[4];
    #pragma unroll
    for (int t = 0; t < 2; t++) af[t]  = *(const bf16x8*)&As[wave*32 + t*16 + l16][quad*8];
    #pragma unroll
    for (int t = 0; t < 4; t++) bfr[t] = *(const bf16x8*)&Bs[t*16 + l16][quad*8];
    #pragma unroll
    for (int ti = 0; ti < 2; ti++)
      #pragma unroll
      for (int jn = 0; jn < 4; jn++)
        acc[ti][jn] = __builtin_amdgcn_mfma_f32_16x16x32_bf16(af[ti], bfr[jn], acc[ti][jn], 0, 0, 0);
    __syncthreads();
  }
  #pragma unroll
  for (int jn = 0; jn < 4; jn++) {
    int col = col_base + n0 + jn*16 + l16;
    int bb = col >> 12;
    int np = col & 4095;
    #pragma unroll
    for (int ti = 0; ti < 2; ti++) {
      int o = m0 + wave*32 + ti*16 + quad*4;
      #pragma unroll
      for (int r = 0; r < 4; r++) {
        int oo = o + r;
        size_t addr = ((size_t)(bb*256 + oo))*4096 + np;
        out[addr] = acc[ti][jn][r] + bias[oo] + resid[addr];
      }
    }
  }
}

extern "C" void kernel_launch(void* const* d_in, const int* in_sizes, int n_in,
                              void* d_out, int out_size, void* d_ws, size_t ws_size,
                              hipStream_t stream) {
  const float* x      = (const float*)d_in[0];
  const float* gamma  = (const float*)d_in[1];
  const float* beta   = (const float*)d_in[2];
  const float* w_qkv  = (const float*)d_in[3];
  const float* b_qkv  = (const float*)d_in[4];
  const float* w_proj = (const float*)d_in[5];
  const float* b_proj = (const float*)d_in[6];
  float* out = (float*)d_out;

  char* ws = (char*)d_ws;
  float*  stats    = (float*)ws;                   // 256 B
  float2* partial  = (float2*)(ws + 1024);         // 2048 B
  ushort_t* wqkv_bf  = (ushort_t*)(ws + 4096);     // 393216 B
  ushort_t* wproj_bf = (ushort_t*)(ws + 397312);   // 131072 B
  char* big = ws + 528384;

  gn_stats1<<<dim3(256), dim3(256), 0, stream>>>(x, partial);
  gn_stats2<<<dim3(1), dim3(64), 0, stream>>>(partial, stats);
  wconv2<<<dim3(256), dim3(256), 0, stream>>>(w_qkv, w_proj, wqkv_bf, wproj_bf);

  // Full path: q 8.39M + k 8.39M + vt 8.39M + xn(nb=2) 4.19M = 29,888,512 B.
  if (ws_size >= (size_t)528384 + 3*(size_t)8388608 + (size_t)4194304) {
    ushort_t* q    = (ushort_t*)big;
    ushort_t* kbuf = (ushort_t*)(big + (size_t)8388608);
    ushort_t* vt   = (ushort_t*)(big + (size_t)16777216);
    ushort_t* xn   = (ushort_t*)(big + (size_t)25165824);
    for (int c = 0; c < 2; c++) {
      int b0 = c * 2;
      gn_apply_t<<<dim3(256), dim3(256), 0, stream>>>(x, stats, gamma, beta, xn, b0);
      gemm_qkv<<<dim3(768), dim3(256), 0, stream>>>(xn, wqkv_bf, b_qkv, q, kbuf, vt, b0);
    }
    attn<<<dim3(512), dim3(256), 0, stream>>>(q, kbuf, vt);
    gemm_proj<<<dim3(512), dim3(256), 0, stream>>>(wproj_bf, q, b_proj, x, out, 0);
  } else {
    // Per-batch fallback: 4 x 2.1M = 8.4M after fixed region.
    ushort_t* q_c  = (ushort_t*)big;
    ushort_t* k_c  = (ushort_t*)(big + (size_t)2097152);
    ushort_t* vt_c = (ushort_t*)(big + (size_t)4194304);
    ushort_t* xn_c = (ushort_t*)(big + (size_t)6291456);
    for (int b0 = 0; b0 < 4; b0++) {
      gn_apply_t<<<dim3(128), dim3(256), 0, stream>>>(x, stats, gamma, beta, xn_c, b0);
      gemm_qkv<<<dim3(384), dim3(256), 0, stream>>>(xn_c, wqkv_bf, b_qkv, q_c, k_c, vt_c, 0);
      attn<<<dim3(128), dim3(256), 0, stream>>>(q_c, k_c, vt_c);
      gemm_proj<<<dim3(128), dim3(256), 0, stream>>>(wproj_bf, q_c, b_proj, x, out, b0*4096);
    }
  }
}